// Round 1
// baseline (93.625 us; speedup 1.0000x reference)
//
#include <hip/hip_runtime.h>

// ParallelBellowsLayers: out[b,c] = relu( sum_e relu(x[b,c]*w1[c,e]+b1[c,e]) * w2[c,e] + b2[c] )
// B=128, C=40000, E=16. Output layout is flat (B, C) — identical indexing to x.
//
// Strategy: per-channel params (49 floats) live in registers; each thread owns
// one channel c and a chunk of 32 batches, so params are loaded from HBM/L3
// once per 32 elements instead of once per element (avoids the ~1 GB L2
// traffic a thread-per-element kernel would generate).

#define N_GENES 20000
#define N_TECH  2
#define N_EXP   16
#define BATCH   128
#define C_DIM   (N_GENES * N_TECH)   // 40000
#define B_CHUNK 32
#define BLOCK   256

__global__ __launch_bounds__(BLOCK, 2)
void bellows_kernel(const float* __restrict__ x,
                    const float* __restrict__ w1,
                    const float* __restrict__ b1,
                    const float* __restrict__ w2,
                    const float* __restrict__ b2,
                    float* __restrict__ out)
{
    const int c = blockIdx.x * BLOCK + threadIdx.x;
    if (c >= C_DIM) return;
    const int b0 = blockIdx.y * B_CHUNK;

    // ---- load per-channel params into registers (float4: rows are 64B-aligned) ----
    const float4* w1v = (const float4*)(w1 + (size_t)c * N_EXP);
    const float4* b1v = (const float4*)(b1 + (size_t)c * N_EXP);
    const float4* w2v = (const float4*)(w2 + (size_t)c * N_EXP);

    float w1r[N_EXP], b1r[N_EXP], w2r[N_EXP];
    #pragma unroll
    for (int i = 0; i < N_EXP / 4; ++i) {
        float4 a = w1v[i], bq = b1v[i], w = w2v[i];
        w1r[4*i+0] = a.x;  w1r[4*i+1] = a.y;  w1r[4*i+2] = a.z;  w1r[4*i+3] = a.w;
        b1r[4*i+0] = bq.x; b1r[4*i+1] = bq.y; b1r[4*i+2] = bq.z; b1r[4*i+3] = bq.w;
        w2r[4*i+0] = w.x;  w2r[4*i+1] = w.y;  w2r[4*i+2] = w.z;  w2r[4*i+3] = w.w;
    }
    const float bias2 = b2[c];

    // ---- batch loop: coalesced x load (lane i -> c0+i, contiguous), compute, store ----
    #pragma unroll 4
    for (int bb = 0; bb < B_CHUNK; ++bb) {
        const int b = b0 + bb;
        const float xv = x[(size_t)b * C_DIM + c];
        float acc = bias2;
        #pragma unroll
        for (int e = 0; e < N_EXP; ++e) {
            float h = fmaxf(fmaf(xv, w1r[e], b1r[e]), 0.0f);
            acc = fmaf(h, w2r[e], acc);
        }
        out[(size_t)b * C_DIM + c] = fmaxf(acc, 0.0f);
    }
}

extern "C" void kernel_launch(void* const* d_in, const int* in_sizes, int n_in,
                              void* d_out, int out_size, void* d_ws, size_t ws_size,
                              hipStream_t stream) {
    const float* x  = (const float*)d_in[0];
    const float* w1 = (const float*)d_in[1];
    const float* b1 = (const float*)d_in[2];
    const float* w2 = (const float*)d_in[3];
    const float* b2 = (const float*)d_in[4];
    float* out = (float*)d_out;

    dim3 grid((C_DIM + BLOCK - 1) / BLOCK, BATCH / B_CHUNK);
    bellows_kernel<<<grid, dim3(BLOCK), 0, stream>>>(x, w1, b1, w2, b2, out);
}